// Round 13
// baseline (304.670 us; speedup 1.0000x reference)
//
#include <hip/hip_runtime.h>
#include <hip/hip_bf16.h>
#include <cmath>

#define BB 8
#define PP 16384
#define CC 256
#define NCLUS 8
#define BPROWS (BB*PP)

typedef unsigned int uint;
typedef unsigned short ushort;
typedef __bf16 bf16x8 __attribute__((ext_vector_type(8)));
typedef float f32x16 __attribute__((ext_vector_type(16)));

__device__ __forceinline__ ushort f2bf(float x){ __hip_bfloat16 h = __float2bfloat16(x); return *(ushort*)&h; }
__device__ __forceinline__ uint pk2(float a, float b){ return (uint)f2bf(a) | ((uint)f2bf(b) << 16); }

// ---------------- weights -> bf16, and zero rsum ----------------
__global__ __launch_bounds__(256) void wcvt(const float* __restrict__ Wp,
    const float* __restrict__ Wr, ushort* __restrict__ Wpb, ushort* __restrict__ Wrb,
    float* __restrict__ rsum) {
  int i = blockIdx.x*256 + threadIdx.x;           // 16384 threads
  float4 a = *(const float4*)(Wp + (size_t)i*4);
  float4 b = *(const float4*)(Wr + (size_t)i*4);
  *(uint2*)(Wpb + (size_t)i*4) = make_uint2(pk2(a.x,a.y), pk2(a.z,a.w));
  *(uint2*)(Wrb + (size_t)i*4) = make_uint2(pk2(b.x,b.y), pk2(b.z,b.w));
  float4 z = make_float4(0.f,0.f,0.f,0.f);
  *(float4*)(rsum + (size_t)i*8)     = z;          // 131072 floats zeroed
  *(float4*)(rsum + (size_t)i*8 + 4) = z;
}

// ---------------- MFMA sims: one wave computes 8 sims for 32 points ----------------
__device__ __forceinline__ void sims_mfma(const ushort* __restrict__ nb_base,
    const ushort* __restrict__ cnb, int lane, float* s) {
  const int pcol = lane & 31;
  const int kb   = (lane >> 5) << 3;
  const ushort* arow = cnb + (size_t)(pcol & 7)*CC + kb;
  const ushort* brow = nb_base + (size_t)pcol*CC + kb;
  const bool azero = pcol >= 8;
  bf16x8 z;
  #pragma unroll
  for (int j = 0; j < 8; ++j) z[j] = (__bf16)0.0f;
  f32x16 acc;
  #pragma unroll
  for (int r = 0; r < 16; ++r) acc[r] = 0.0f;
  #pragma unroll
  for (int st = 0; st < 16; ++st) {
    bf16x8 af = *(const bf16x8*)(arow + st*16);
    if (azero) af = z;
    bf16x8 bg = *(const bf16x8*)(brow + st*16);
    acc = __builtin_amdgcn_mfma_f32_32x32x16_bf16(af, bg, acc, 0, 0, 0);
  }
  float sh[4];
  #pragma unroll
  for (int r = 0; r < 4; ++r) sh[r] = __shfl_xor(acc[r], 32);
  const bool hi = lane >= 32;
  #pragma unroll
  for (int r = 0; r < 4; ++r) {
    s[r]     = hi ? sh[r]  : acc[r];
    s[r + 4] = hi ? acc[r] : sh[r];
  }
}

// ---------------- MFMA GEMM, BN=128 (grid 1024 x 2), 36 KB LDS -> 4 blocks/CU ----------------
// PROJ: D bf16 (nodes) + atomic partial row-sumsq into rsum (2 adds/point, deterministic).
// !PROJ: computes its own W8 (sims+softmax, waves 0-3, overlapped with tile-0 staging);
//        D fp32 + rank-8 correction W8@CR in epilogue.  A = F_p f32, cvt in reg-staging.
template<bool PROJ>
__global__ __launch_bounds__(512) void gemm_bf16(const float* __restrict__ A,
    const ushort* __restrict__ Wb, const float* __restrict__ bias,
    void* __restrict__ Dv, float* __restrict__ rsum,
    const float* __restrict__ CR,
    const ushort* __restrict__ nbf, const ushort* __restrict__ cnormbf) {
  __shared__ __align__(16) char AlB[128*64*2];   // 16 KB
  __shared__ __align__(16) char WlB[128*64*2];   // 16 KB (half-N tile)
  __shared__ __align__(16) float shr8[128][8];   // 4 KB: PROJ partial-sumsq / !PROJ W8
  const int t  = threadIdx.x;
  const int p0 = blockIdx.x * 128;
  const int n0 = blockIdx.y * 128;
  const int lane = t & 63;
  const int w  = t >> 6;
  const int wr = w >> 1, wc = w & 1;             // 4M x 2N waves

  // ---- A staging map: linear global f32 source chunk, swizzled LDS dest
  int aoff[2]; size_t agb[2];
  #pragma unroll
  for (int i = 0; i < 2; ++i) {
    int S = i*512 + t, row = S >> 3, sc = S & 7;
    aoff[i] = row*128 + ((sc*16) ^ ((row & 7) << 4));
    agb[i]  = (size_t)(p0 + row)*CC + sc*8;
  }
  // ---- W staging map: inverse-swizzled global source, linear LDS dest (2 chunks/thread)
  const ushort* wsrc[2]; char* wdst[2];
  #pragma unroll
  for (int i = 0; i < 2; ++i) {
    int S = i*512 + t, row = S >> 3, sc = S & 7;
    wsrc[i] = Wb + (size_t)(n0 + row)*CC + ((sc ^ (row & 7)) << 3);
    wdst[i] = WlB + (size_t)S*16;
  }
  const int arow = (wr << 5) + (lane & 31);
  const int brow = (wc << 6) + (lane & 31);
  const int kb0  = (lane >> 5) << 4;

  uint4 ra[2];
  auto LOADA = [&](int ks) {             // f32 -> packed bf16 regs
    #pragma unroll
    for (int i = 0; i < 2; ++i) {
      float4 v0 = *(const float4*)(A + agb[i] + ks*64);
      float4 v1 = *(const float4*)(A + agb[i] + ks*64 + 4);
      ra[i] = make_uint4(pk2(v0.x,v0.y), pk2(v0.z,v0.w), pk2(v1.x,v1.y), pk2(v1.z,v1.w));
    }
  };
  auto WRITEA = [&]() {
    #pragma unroll
    for (int i = 0; i < 2; ++i) *(uint4*)(AlB + aoff[i]) = ra[i];
  };
  auto STAGEW = [&](int ks) {
    #pragma unroll
    for (int i = 0; i < 2; ++i)
      __builtin_amdgcn_global_load_lds(
          (const __attribute__((address_space(1))) uint*)(wsrc[i] + ks*64),
          (__attribute__((address_space(3))) uint*)wdst[i], 16, 0, 0);
  };

  f32x16 acc[2];                          // fn = 0,1
  #pragma unroll
  for (int fn = 0; fn < 2; ++fn)
    #pragma unroll
    for (int r = 0; r < 16; ++r) acc[fn][r] = 0.0f;

  // ---- prologue: stage tile 0 (+ !PROJ: compute this block's W8 under the staging loads)
  LOADA(0); STAGEW(0);
  if constexpr (!PROJ) {
    if (w < 4) {                         // waves 0-3: 32 points each
      const size_t p0w = (size_t)p0 + w*32;
      float s[8];
      sims_mfma(nbf + p0w*CC, cnormbf + (size_t)(blockIdx.x >> 7)*NCLUS*CC, lane, s);
      const int pcol = lane & 31;
      const float rn10 = 10.0f / fmaxf(sqrtf(rsum[p0w + pcol]), 1e-12f);
      float m = -1e30f;
      #pragma unroll
      for (int k = 0; k < 8; ++k) { s[k] *= rn10; m = fmaxf(m, s[k]); }
      float wgt[8], sw = 0.0f;
      #pragma unroll
      for (int k = 0; k < 8; ++k) { wgt[k] = __expf(s[k] - m); sw += wgt[k]; }
      const float inv = 1.0f / sw;
      if (lane < 32) {
        float* wp = &shr8[w*32 + pcol][0];
        *(float4*)(wp)     = make_float4(wgt[0]*inv, wgt[1]*inv, wgt[2]*inv, wgt[3]*inv);
        *(float4*)(wp + 4) = make_float4(wgt[4]*inv, wgt[5]*inv, wgt[6]*inv, wgt[7]*inv);
      }
    }
  }
  WRITEA();
  __syncthreads();                       // tile 0 ready (+ W8 visible)

  #pragma unroll
  for (int ks = 0; ks < 4; ++ks) {
    if (ks < 3) LOADA(ks + 1);           // next A in flight under MFMAs
    bf16x8 af[4], bg[2][4];
    #pragma unroll
    for (int kq = 0; kq < 4; ++kq) {
      int row = arow;
      int off = row*128 + (((kq << 5) + kb0) ^ ((row & 7) << 4));
      af[kq] = *(const bf16x8*)(AlB + off);
    }
    #pragma unroll
    for (int fn = 0; fn < 2; ++fn)
      #pragma unroll
      for (int kq = 0; kq < 4; ++kq) {
        int row = brow + (fn << 5);
        int off = row*128 + (((kq << 5) + kb0) ^ ((row & 7) << 4));
        bg[fn][kq] = *(const bf16x8*)(WlB + off);
      }
    #pragma unroll
    for (int kq = 0; kq < 4; ++kq)
      #pragma unroll
      for (int fn = 0; fn < 2; ++fn)
        acc[fn] = __builtin_amdgcn_mfma_f32_32x32x16_bf16(
            af[kq], bg[fn][kq], acc[fn], 0, 0, 0);
    if (ks < 3) {
      __syncthreads();                   // tile ks reads complete
      STAGEW(ks + 1);
      WRITEA();
      __syncthreads();                   // tile ks+1 ready
    }
  }

  // --- epilogue ---
  const int colb = n0 + (wc << 6) + (lane & 31);
  const float b0 = bias[colb], b1 = bias[colb + 32];
  float cr0[8], cr1[8];
  if constexpr (!PROJ) {
    const float* crb = CR + (size_t)(blockIdx.x >> 7)*NCLUS*CC;
    #pragma unroll
    for (int k = 0; k < 8; ++k) { cr0[k] = crb[k*CC + colb]; cr1[k] = crb[k*CC + colb + 32]; }
  }
  float rs[16];
  #pragma unroll
  for (int r = 0; r < 16; ++r) {
    int rowin = (r & 3) + ((r >> 2) << 3) + ((lane >> 5) << 2);
    int r128  = (wr << 5) + rowin;
    size_t grow = (size_t)(p0 + r128);
    float v0 = acc[0][r] + b0;
    float v1 = acc[1][r] + b1;
    if constexpr (PROJ) {
      ushort* D = (ushort*)Dv;
      D[grow*CC + colb]      = f2bf(v0);
      D[grow*CC + colb + 32] = f2bf(v1);
      rs[r] = v0*v0 + v1*v1;
    } else {
      float4 ua = *(const float4*)&shr8[r128][0];   // W8 from LDS (broadcast)
      float4 ub = *(const float4*)&shr8[r128][4];
      v0 += ua.x*cr0[0] + ua.y*cr0[1] + ua.z*cr0[2] + ua.w*cr0[3]
          + ub.x*cr0[4] + ub.y*cr0[5] + ub.z*cr0[6] + ub.w*cr0[7];
      v1 += ua.x*cr1[0] + ua.y*cr1[1] + ua.z*cr1[2] + ua.w*cr1[3]
          + ub.x*cr1[4] + ub.y*cr1[5] + ub.z*cr1[6] + ub.w*cr1[7];
      float* D = (float*)Dv;
      D[grow*CC + colb]      = v0;
      D[grow*CC + colb + 32] = v1;
    }
  }
  if constexpr (PROJ) {
    #pragma unroll
    for (int m = 1; m < 32; m <<= 1)
      #pragma unroll
      for (int r = 0; r < 16; ++r) rs[r] += __shfl_xor(rs[r], m);
    __syncthreads();                     // shr8 (A-stage scratch) free for reuse
    if ((lane & 31) == 0) {
      #pragma unroll
      for (int r = 0; r < 16; ++r) {
        int rowin = (r & 3) + ((r >> 2) << 3) + ((lane >> 5) << 2);
        shr8[(wr << 5) + rowin][wc] = rs[r];
      }
    }
    __syncthreads();
    if (t < 128) {
      // one atomic per point per block; exactly 2 blocks contribute -> deterministic sum
      atomicAdd(&rsum[p0 + t], shr8[t][0] + shr8[t][1]);
    }
  }
}

// ---------------- merged: init centers from nodes + norm + zero accs ----------------
__global__ __launch_bounds__(256) void centers_init(const ushort* __restrict__ nbf,
    ushort* __restrict__ cnormbf, float* __restrict__ accs, float* __restrict__ counts) {
  const int idxs[8] = {0, 2340, 4680, 7021, 9361, 11702, 14042, 16383};
  const int row = blockIdx.x;            // b*8 + k
  const int b = row >> 3, k = row & 7;
  const int t = threadIdx.x;
  float c = __uint_as_float(((uint)nbf[((size_t)b*PP + idxs[k])*CC + t]) << 16);
  float s2 = c*c;
  #pragma unroll
  for (int o = 32; o; o >>= 1) s2 += __shfl_xor(s2, o);
  __shared__ float ps[4];
  if ((t & 63) == 0) ps[t >> 6] = s2;
  __syncthreads();
  float tot = ps[0] + ps[1] + ps[2] + ps[3];
  cnormbf[(size_t)row*CC + t] = f2bf(c * (1.0f / fmaxf(sqrtf(tot), 1e-12f)));
  #pragma unroll
  for (int s = 0; s < 8; ++s) accs[((size_t)s*64 + row)*CC + t] = 0.0f;
  if (t == 0) counts[row] = 0.0f;
}

// accs -> cnormbf; DO_CR: also CR[row][t] = dot(center_row, Wr[t]); re-zero accs/counts
template<bool DO_CR>
__global__ __launch_bounds__(256) void centers_finalize(float* __restrict__ accs,
    float* __restrict__ counts, ushort* __restrict__ cnormbf,
    const float* __restrict__ Wr, float* __restrict__ CR) {
  __shared__ float cenL[CC];
  const int row = blockIdx.x;
  const int t = threadIdx.x;
  float v = 0.0f;
  #pragma unroll
  for (int s = 0; s < 8; ++s) {
    v += accs[((size_t)s*64 + row)*CC + t];
    accs[((size_t)s*64 + row)*CC + t] = 0.0f;
  }
  float cnt = fmaxf(counts[row], 1.0f);
  float c = v / cnt;
  if constexpr (DO_CR) cenL[t] = c;
  float s2 = c*c;
  #pragma unroll
  for (int o = 32; o; o >>= 1) s2 += __shfl_xor(s2, o);
  __shared__ float ps[4];
  if ((t & 63) == 0) ps[t >> 6] = s2;
  __syncthreads();
  float tot = ps[0] + ps[1] + ps[2] + ps[3];
  cnormbf[(size_t)row*CC + t] = f2bf(c * (1.0f / fmaxf(sqrtf(tot), 1e-12f)));
  if (t == 0) counts[row] = 0.0f;
  if constexpr (DO_CR) {
    float a = 0.0f;
    const float* wrow = Wr + (size_t)t*CC;
    #pragma unroll 4
    for (int j = 0; j < CC; j += 4) {
      float4 wv = *(const float4*)(wrow + j);
      float4 cv = *(const float4*)&cenL[j];
      a += cv.x*wv.x + cv.y*wv.y + cv.z*wv.z + cv.w*wv.w;
    }
    CR[(size_t)row*CC + t] = a;
  }
}

// ---------------- assign: MFMA sims + argmax, column-parallel accumulate ----------------
__global__ __launch_bounds__(256) void assign_mfma(const ushort* __restrict__ nbf,
    const ushort* __restrict__ cnormbf, float* __restrict__ accs, float* __restrict__ counts) {
  __shared__ int assignL[128];
  __shared__ int cntL[NCLUS];
  const int t = threadIdx.x;
  const int wave = t >> 6, lane = t & 63;
  const int b = blockIdx.x >> 7;
  if (t < NCLUS) cntL[t] = 0;
  __syncthreads();
  const size_t p0w = (size_t)blockIdx.x*128 + wave*32;
  float s[8];
  sims_mfma(nbf + p0w*CC, cnormbf + (size_t)b*NCLUS*CC, lane, s);
  if (lane < 32) {
    int best = 0; float bs = s[0];
    #pragma unroll
    for (int k = 1; k < 8; ++k) if (s[k] > bs) { bs = s[k]; best = k; }
    assignL[wave*32 + lane] = best;
    atomicAdd(&cntL[best], 1);
  }
  __syncthreads();
  float a[8] = {0,0,0,0,0,0,0,0};
  const ushort* base = nbf + (size_t)blockIdx.x*128*CC;
  #pragma unroll 4
  for (int i = 0; i < 128; ++i) {
    int asg = __builtin_amdgcn_readfirstlane(assignL[i]);
    float v = __uint_as_float(((uint)base[(size_t)i*CC + t]) << 16);
    if      (asg == 0) a[0] += v;
    else if (asg == 1) a[1] += v;
    else if (asg == 2) a[2] += v;
    else if (asg == 3) a[3] += v;
    else if (asg == 4) a[4] += v;
    else if (asg == 5) a[5] += v;
    else if (asg == 6) a[6] += v;
    else               a[7] += v;
  }
  const int slot = blockIdx.x & 7;
  float* dst = accs + ((size_t)slot*BB + b)*NCLUS*CC;
  #pragma unroll
  for (int k = 0; k < 8; ++k) atomicAdd(&dst[k*CC + t], a[k]);
  if (t < NCLUS) atomicAdd(&counts[b*NCLUS + t], (float)cntL[t]);
}

extern "C" void kernel_launch(void* const* d_in, const int* in_sizes, int n_in,
                              void* d_out, int out_size, void* d_ws, size_t ws_size,
                              hipStream_t stream) {
  const float* F_p      = (const float*)d_in[0];
  const float* proj_w   = (const float*)d_in[1];
  const float* proj_b   = (const float*)d_in[2];
  const float* refine_w = (const float*)d_in[3];
  const float* refine_b = (const float*)d_in[4];
  float* out = (float*)d_out;

  char* ws = (char*)d_ws;
  ushort* nbf    = (ushort*)ws;                                  // 64 MiB
  float*  rsum   = (float*)(ws + (size_t)BPROWS*CC*2);           // 512 KiB
  float*  accs   = rsum + BPROWS;                                // 512 KiB
  float*  counts = accs + 8*BB*NCLUS*CC;                         // 256 B
  float*  CR     = counts + 64;                                  // 64 KiB
  ushort* cnormbf= (ushort*)(CR + BB*NCLUS*CC);                  // 32 KiB
  ushort* Wpb    = cnormbf + BB*NCLUS*CC;                        // 128 KiB
  ushort* Wrb    = Wpb + CC*CC;                                  // 128 KiB

  wcvt<<<64, 256, 0, stream>>>(proj_w, refine_w, Wpb, Wrb, rsum);
  gemm_bf16<true><<<dim3(1024, 2), 512, 0, stream>>>(F_p, Wpb, proj_b, nbf, rsum,
                                                     nullptr, nullptr, nullptr);
  centers_init<<<64, 256, 0, stream>>>(nbf, cnormbf, accs, counts);
  for (int it = 0; it < 3; ++it) {
    assign_mfma<<<1024, 256, 0, stream>>>(nbf, cnormbf, accs, counts);
    if (it < 2) centers_finalize<false><<<64, 256, 0, stream>>>(accs, counts, cnormbf, nullptr, nullptr);
    else        centers_finalize<true ><<<64, 256, 0, stream>>>(accs, counts, cnormbf, refine_w, CR);
  }
  gemm_bf16<false><<<dim3(1024, 2), 512, 0, stream>>>(F_p, Wrb, refine_b, out, rsum,
                                                      CR, nbf, cnormbf);
}

// Round 14
// 274.162 us; speedup vs baseline: 1.1113x; 1.1113x over previous
//
#include <hip/hip_runtime.h>
#include <hip/hip_bf16.h>
#include <cmath>

#define BB 8
#define PP 16384
#define CC 256
#define NCLUS 8
#define BPROWS (BB*PP)

typedef unsigned int uint;
typedef unsigned short ushort;
typedef __bf16 bf16x8 __attribute__((ext_vector_type(8)));
typedef float f32x16 __attribute__((ext_vector_type(16)));

__device__ __forceinline__ ushort f2bf(float x){ __hip_bfloat16 h = __float2bfloat16(x); return *(ushort*)&h; }
__device__ __forceinline__ uint pk2(float a, float b){ return (uint)f2bf(a) | ((uint)f2bf(b) << 16); }

// ---------------- one-shot bf16 conversion of both weight matrices ----------------
__global__ __launch_bounds__(256) void wcvt(const float* __restrict__ Wp,
    const float* __restrict__ Wr, ushort* __restrict__ Wpb, ushort* __restrict__ Wrb) {
  int i = blockIdx.x*256 + threadIdx.x;
  float4 a = *(const float4*)(Wp + (size_t)i*4);
  float4 b = *(const float4*)(Wr + (size_t)i*4);
  *(uint2*)(Wpb + (size_t)i*4) = make_uint2(pk2(a.x,a.y), pk2(a.z,a.w));
  *(uint2*)(Wrb + (size_t)i*4) = make_uint2(pk2(b.x,b.y), pk2(b.z,b.w));
}

// ---------------- MFMA sims: one wave computes 8 sims for 32 points ----------------
__device__ __forceinline__ void sims_mfma(const ushort* __restrict__ nb_base,
    const ushort* __restrict__ cnb, int lane, float* s) {
  const int pcol = lane & 31;
  const int kb   = (lane >> 5) << 3;
  const ushort* arow = cnb + (size_t)(pcol & 7)*CC + kb;
  const ushort* brow = nb_base + (size_t)pcol*CC + kb;
  const bool azero = pcol >= 8;
  bf16x8 z;
  #pragma unroll
  for (int j = 0; j < 8; ++j) z[j] = (__bf16)0.0f;
  f32x16 acc;
  #pragma unroll
  for (int r = 0; r < 16; ++r) acc[r] = 0.0f;
  #pragma unroll
  for (int st = 0; st < 16; ++st) {
    bf16x8 af = *(const bf16x8*)(arow + st*16);
    if (azero) af = z;
    bf16x8 bg = *(const bf16x8*)(brow + st*16);
    acc = __builtin_amdgcn_mfma_f32_32x32x16_bf16(af, bg, acc, 0, 0, 0);
  }
  float sh[4];
  #pragma unroll
  for (int r = 0; r < 4; ++r) sh[r] = __shfl_xor(acc[r], 32);
  const bool hi = lane >= 32;
  #pragma unroll
  for (int r = 0; r < 4; ++r) {
    s[r]     = hi ? sh[r]  : acc[r];
    s[r + 4] = hi ? acc[r] : sh[r];
  }
}

// ---------------- MFMA GEMM (R8/R12 structure, A = F_p f32 reg-staged for BOTH) ----------------
// PROJ: D bf16 (nodes) + per-row rnorm.
// !PROJ: computes its own W8 (sims+softmax, waves 0-3, overlapped with tile-0 staging);
//        D fp32 (NON-TEMPORAL stores — out is write-once, keep F_p/nbf in L3) + W8@CR.
template<bool PROJ>
__global__ __launch_bounds__(512) void gemm_bf16(const float* __restrict__ A,
    const ushort* __restrict__ Wb, const float* __restrict__ bias,
    void* __restrict__ Dv, float* __restrict__ rnorm,
    const float* __restrict__ CR,
    const ushort* __restrict__ nbf, const ushort* __restrict__ cnormbf) {
  __shared__ __align__(16) char AlB[128*64*2];   // 16 KB
  __shared__ __align__(16) char WlB[256*64*2];   // 32 KB
  __shared__ __align__(16) float shr8[128][8];   // 4 KB: PROJ rnp cols / !PROJ W8
  const int t  = threadIdx.x;
  const int p0 = blockIdx.x * 128;
  const int lane = t & 63;
  const int w  = t >> 6;
  const int wr = w >> 2, wc = w & 3;

  // ---- A staging map: linear global f32 source chunk, swizzled LDS dest
  int aoff[2]; size_t agb[2];
  #pragma unroll
  for (int i = 0; i < 2; ++i) {
    int S = i*512 + t, row = S >> 3, sc = S & 7;
    aoff[i] = row*128 + ((sc*16) ^ ((row & 7) << 4));
    agb[i]  = (size_t)(p0 + row)*CC + sc*8;
  }
  const ushort* wsrc[4]; char* wdst[4];
  #pragma unroll
  for (int i = 0; i < 4; ++i) {
    int S = i*512 + t, row = S >> 3, sc = S & 7;
    wsrc[i] = Wb + (size_t)row*CC + ((sc ^ (row & 7)) << 3);
    wdst[i] = WlB + (size_t)S*16;
  }
  const int arow = (wr << 6) + (lane & 31);
  const int brow = (wc << 6) + (lane & 31);
  const int kb0  = (lane >> 5) << 4;

  uint4 ra[2];
  auto LOADA = [&](int ks) {             // f32 -> packed bf16 regs
    #pragma unroll
    for (int i = 0; i < 2; ++i) {
      float4 v0 = *(const float4*)(A + agb[i] + ks*64);
      float4 v1 = *(const float4*)(A + agb[i] + ks*64 + 4);
      ra[i] = make_uint4(pk2(v0.x,v0.y), pk2(v0.z,v0.w), pk2(v1.x,v1.y), pk2(v1.z,v1.w));
    }
  };
  auto WRITEA = [&]() {                  // LDS only (swizzled)
    #pragma unroll
    for (int i = 0; i < 2; ++i) *(uint4*)(AlB + aoff[i]) = ra[i];
  };
  auto STAGEW = [&](int ks) {
    #pragma unroll
    for (int i = 0; i < 4; ++i)
      __builtin_amdgcn_global_load_lds(
          (const __attribute__((address_space(1))) uint*)(wsrc[i] + ks*64),
          (__attribute__((address_space(3))) uint*)wdst[i], 16, 0, 0);
  };

  f32x16 acc[2][2];
  #pragma unroll
  for (int fm = 0; fm < 2; ++fm)
    #pragma unroll
    for (int fn = 0; fn < 2; ++fn)
      #pragma unroll
      for (int r = 0; r < 16; ++r) acc[fm][fn][r] = 0.0f;

  // ---- prologue: stage tile 0 (+ !PROJ: compute this block's W8 under the staging loads)
  LOADA(0); STAGEW(0);
  if constexpr (!PROJ) {
    if (w < 4) {                         // waves 0-3: 32 points each
      const size_t p0w = (size_t)p0 + w*32;
      float s[8];
      sims_mfma(nbf + p0w*CC, cnormbf + (size_t)(blockIdx.x >> 7)*NCLUS*CC, lane, s);
      const int pcol = lane & 31;
      const float rn10 = rnorm[p0w + pcol] * 10.0f;
      float m = -1e30f;
      #pragma unroll
      for (int k = 0; k < 8; ++k) { s[k] *= rn10; m = fmaxf(m, s[k]); }
      float wgt[8], sw = 0.0f;
      #pragma unroll
      for (int k = 0; k < 8; ++k) { wgt[k] = __expf(s[k] - m); sw += wgt[k]; }
      const float inv = 1.0f / sw;
      if (lane < 32) {
        float* wp = &shr8[w*32 + pcol][0];
        *(float4*)(wp)     = make_float4(wgt[0]*inv, wgt[1]*inv, wgt[2]*inv, wgt[3]*inv);
        *(float4*)(wp + 4) = make_float4(wgt[4]*inv, wgt[5]*inv, wgt[6]*inv, wgt[7]*inv);
      }
    }
  }
  WRITEA();
  __syncthreads();                       // tile 0 ready (+ W8 visible)

  #pragma unroll
  for (int ks = 0; ks < 4; ++ks) {
    if (ks < 3) LOADA(ks + 1);           // next A in flight under MFMAs
    bf16x8 af[2][4], bg[2][4];
    #pragma unroll
    for (int fm = 0; fm < 2; ++fm)
      #pragma unroll
      for (int kq = 0; kq < 4; ++kq) {
        int row = arow + (fm << 5);
        int off = row*128 + (((kq << 5) + kb0) ^ ((row & 7) << 4));
        af[fm][kq] = *(const bf16x8*)(AlB + off);
      }
    #pragma unroll
    for (int fn = 0; fn < 2; ++fn)
      #pragma unroll
      for (int kq = 0; kq < 4; ++kq) {
        int row = brow + (fn << 5);
        int off = row*128 + (((kq << 5) + kb0) ^ ((row & 7) << 4));
        bg[fn][kq] = *(const bf16x8*)(WlB + off);
      }
    #pragma unroll
    for (int kq = 0; kq < 4; ++kq)
      #pragma unroll
      for (int fm = 0; fm < 2; ++fm)
        #pragma unroll
        for (int fn = 0; fn < 2; ++fn)
          acc[fm][fn] = __builtin_amdgcn_mfma_f32_32x32x16_bf16(
              af[fm][kq], bg[fn][kq], acc[fm][fn], 0, 0, 0);
    if (ks < 3) {
      __syncthreads();                   // tile ks reads complete
      STAGEW(ks + 1);
      WRITEA();
      __syncthreads();                   // tile ks+1 ready
    }
  }

  // --- epilogue ---
  const int colb = (wc << 6) + (lane & 31);
  const float b0 = bias[colb], b1 = bias[colb + 32];
  float cr0[8], cr1[8];
  if constexpr (!PROJ) {
    const float* crb = CR + (size_t)(blockIdx.x >> 7)*NCLUS*CC;
    #pragma unroll
    for (int k = 0; k < 8; ++k) { cr0[k] = crb[k*CC + colb]; cr1[k] = crb[k*CC + colb + 32]; }
  }
  #pragma unroll
  for (int fm = 0; fm < 2; ++fm) {
    float rs[16];
    #pragma unroll
    for (int r = 0; r < 16; ++r) {
      int rowin = (r & 3) + ((r >> 2) << 3) + ((lane >> 5) << 2);
      int r128  = (wr << 6) + (fm << 5) + rowin;
      size_t grow = (size_t)(p0 + r128);
      float v0 = acc[fm][0][r] + b0;
      float v1 = acc[fm][1][r] + b1;
      if constexpr (PROJ) {
        ushort* D = (ushort*)Dv;
        D[grow*CC + colb]      = f2bf(v0);
        D[grow*CC + colb + 32] = f2bf(v1);
        rs[r] = v0*v0 + v1*v1;
      } else {
        float4 ua = *(const float4*)&shr8[r128][0];   // W8 from LDS (broadcast)
        float4 ub = *(const float4*)&shr8[r128][4];
        v0 += ua.x*cr0[0] + ua.y*cr0[1] + ua.z*cr0[2] + ua.w*cr0[3]
            + ub.x*cr0[4] + ub.y*cr0[5] + ub.z*cr0[6] + ub.w*cr0[7];
        v1 += ua.x*cr1[0] + ua.y*cr1[1] + ua.z*cr1[2] + ua.w*cr1[3]
            + ub.x*cr1[4] + ub.y*cr1[5] + ub.z*cr1[6] + ub.w*cr1[7];
        float* D = (float*)Dv;
        __builtin_nontemporal_store(v0, &D[grow*CC + colb]);       // out: write-once,
        __builtin_nontemporal_store(v1, &D[grow*CC + colb + 32]);  // don't pollute L3
      }
    }
    if constexpr (PROJ) {
      #pragma unroll
      for (int m = 1; m < 32; m <<= 1)
        #pragma unroll
        for (int r = 0; r < 16; ++r) rs[r] += __shfl_xor(rs[r], m);
      if ((lane & 31) == 0) {
        #pragma unroll
        for (int r = 0; r < 16; ++r) {
          int rowin = (r & 3) + ((r >> 2) << 3) + ((lane >> 5) << 2);
          shr8[(wr << 6) + (fm << 5) + rowin][wc] = rs[r];
        }
      }
    }
  }
  if constexpr (PROJ) {
    __syncthreads();
    if (t < 128) {
      float s = shr8[t][0] + shr8[t][1] + shr8[t][2] + shr8[t][3];
      rnorm[p0 + t] = 1.0f / fmaxf(sqrtf(s), 1e-12f);
    }
  }
}

// ---------------- merged: init centers from nodes + norm + zero accs ----------------
__global__ __launch_bounds__(256) void centers_init(const ushort* __restrict__ nbf,
    ushort* __restrict__ cnormbf, float* __restrict__ accs, float* __restrict__ counts) {
  const int idxs[8] = {0, 2340, 4680, 7021, 9361, 11702, 14042, 16383};
  const int row = blockIdx.x;            // b*8 + k
  const int b = row >> 3, k = row & 7;
  const int t = threadIdx.x;
  float c = __uint_as_float(((uint)nbf[((size_t)b*PP + idxs[k])*CC + t]) << 16);
  float s2 = c*c;
  #pragma unroll
  for (int o = 32; o; o >>= 1) s2 += __shfl_xor(s2, o);
  __shared__ float ps[4];
  if ((t & 63) == 0) ps[t >> 6] = s2;
  __syncthreads();
  float tot = ps[0] + ps[1] + ps[2] + ps[3];
  cnormbf[(size_t)row*CC + t] = f2bf(c * (1.0f / fmaxf(sqrtf(tot), 1e-12f)));
  #pragma unroll
  for (int s = 0; s < 8; ++s) accs[((size_t)s*64 + row)*CC + t] = 0.0f;
  if (t == 0) counts[row] = 0.0f;
}

// accs -> cnormbf; DO_CR: also CR[row][t] = dot(center_row, Wr[t]); re-zero accs/counts
template<bool DO_CR>
__global__ __launch_bounds__(256) void centers_finalize(float* __restrict__ accs,
    float* __restrict__ counts, ushort* __restrict__ cnormbf,
    const float* __restrict__ Wr, float* __restrict__ CR) {
  __shared__ float cenL[CC];
  const int row = blockIdx.x;
  const int t = threadIdx.x;
  float v = 0.0f;
  #pragma unroll
  for (int s = 0; s < 8; ++s) {
    v += accs[((size_t)s*64 + row)*CC + t];
    accs[((size_t)s*64 + row)*CC + t] = 0.0f;
  }
  float cnt = fmaxf(counts[row], 1.0f);
  float c = v / cnt;
  if constexpr (DO_CR) cenL[t] = c;
  float s2 = c*c;
  #pragma unroll
  for (int o = 32; o; o >>= 1) s2 += __shfl_xor(s2, o);
  __shared__ float ps[4];
  if ((t & 63) == 0) ps[t >> 6] = s2;
  __syncthreads();
  float tot = ps[0] + ps[1] + ps[2] + ps[3];
  cnormbf[(size_t)row*CC + t] = f2bf(c * (1.0f / fmaxf(sqrtf(tot), 1e-12f)));
  if (t == 0) counts[row] = 0.0f;
  if constexpr (DO_CR) {
    float a = 0.0f;
    const float* wrow = Wr + (size_t)t*CC;
    #pragma unroll 4
    for (int j = 0; j < CC; j += 4) {
      float4 wv = *(const float4*)(wrow + j);
      float4 cv = *(const float4*)&cenL[j];
      a += cv.x*wv.x + cv.y*wv.y + cv.z*wv.z + cv.w*wv.w;
    }
    CR[(size_t)row*CC + t] = a;
  }
}

// ---------------- assign: MFMA sims + argmax, column-parallel accumulate ----------------
__global__ __launch_bounds__(256) void assign_mfma(const ushort* __restrict__ nbf,
    const ushort* __restrict__ cnormbf, float* __restrict__ accs, float* __restrict__ counts) {
  __shared__ int assignL[128];
  __shared__ int cntL[NCLUS];
  const int t = threadIdx.x;
  const int wave = t >> 6, lane = t & 63;
  const int b = blockIdx.x >> 7;
  if (t < NCLUS) cntL[t] = 0;
  __syncthreads();
  const size_t p0w = (size_t)blockIdx.x*128 + wave*32;
  float s[8];
  sims_mfma(nbf + p0w*CC, cnormbf + (size_t)b*NCLUS*CC, lane, s);
  if (lane < 32) {
    int best = 0; float bs = s[0];
    #pragma unroll
    for (int k = 1; k < 8; ++k) if (s[k] > bs) { bs = s[k]; best = k; }
    assignL[wave*32 + lane] = best;
    atomicAdd(&cntL[best], 1);
  }
  __syncthreads();
  float a[8] = {0,0,0,0,0,0,0,0};
  const ushort* base = nbf + (size_t)blockIdx.x*128*CC;
  #pragma unroll 4
  for (int i = 0; i < 128; ++i) {
    int asg = __builtin_amdgcn_readfirstlane(assignL[i]);
    float v = __uint_as_float(((uint)base[(size_t)i*CC + t]) << 16);
    if      (asg == 0) a[0] += v;
    else if (asg == 1) a[1] += v;
    else if (asg == 2) a[2] += v;
    else if (asg == 3) a[3] += v;
    else if (asg == 4) a[4] += v;
    else if (asg == 5) a[5] += v;
    else if (asg == 6) a[6] += v;
    else               a[7] += v;
  }
  const int slot = blockIdx.x & 7;
  float* dst = accs + ((size_t)slot*BB + b)*NCLUS*CC;
  #pragma unroll
  for (int k = 0; k < 8; ++k) atomicAdd(&dst[k*CC + t], a[k]);
  if (t < NCLUS) atomicAdd(&counts[b*NCLUS + t], (float)cntL[t]);
}

extern "C" void kernel_launch(void* const* d_in, const int* in_sizes, int n_in,
                              void* d_out, int out_size, void* d_ws, size_t ws_size,
                              hipStream_t stream) {
  const float* F_p      = (const float*)d_in[0];
  const float* proj_w   = (const float*)d_in[1];
  const float* proj_b   = (const float*)d_in[2];
  const float* refine_w = (const float*)d_in[3];
  const float* refine_b = (const float*)d_in[4];
  float* out = (float*)d_out;

  char* ws = (char*)d_ws;
  ushort* nbf    = (ushort*)ws;                                  // 64 MiB
  float*  rnorm  = (float*)(ws + (size_t)BPROWS*CC*2);           // 512 KiB
  float*  accs   = rnorm + BPROWS;                               // 512 KiB
  float*  counts = accs + 8*BB*NCLUS*CC;                         // 256 B
  float*  CR     = counts + 64;                                  // 64 KiB
  ushort* cnormbf= (ushort*)(CR + BB*NCLUS*CC);                  // 32 KiB
  ushort* Wpb    = cnormbf + BB*NCLUS*CC;                        // 128 KiB
  ushort* Wrb    = Wpb + CC*CC;                                  // 128 KiB

  wcvt<<<64, 256, 0, stream>>>(proj_w, refine_w, Wpb, Wrb);
  gemm_bf16<true><<<1024, 512, 0, stream>>>(F_p, Wpb, proj_b, nbf, rnorm,
                                            nullptr, nullptr, nullptr);
  centers_init<<<64, 256, 0, stream>>>(nbf, cnormbf, accs, counts);
  for (int it = 0; it < 3; ++it) {
    assign_mfma<<<1024, 256, 0, stream>>>(nbf, cnormbf, accs, counts);
    if (it < 2) centers_finalize<false><<<64, 256, 0, stream>>>(accs, counts, cnormbf, nullptr, nullptr);
    else        centers_finalize<true ><<<64, 256, 0, stream>>>(accs, counts, cnormbf, refine_w, CR);
  }
  gemm_bf16<false><<<1024, 512, 0, stream>>>(F_p, Wrb, refine_b, out, rnorm,
                                             CR, nbf, cnormbf);
}

// Round 15
// 255.362 us; speedup vs baseline: 1.1931x; 1.0736x over previous
//
#include <hip/hip_runtime.h>
#include <hip/hip_bf16.h>
#include <cmath>

#define BB 8
#define PP 16384
#define CC 256
#define NCLUS 8
#define BPROWS (BB*PP)

typedef unsigned int uint;
typedef unsigned short ushort;
typedef __bf16 bf16x8 __attribute__((ext_vector_type(8)));
typedef float f32x16 __attribute__((ext_vector_type(16)));

__device__ __forceinline__ ushort f2bf(float x){ __hip_bfloat16 h = __float2bfloat16(x); return *(ushort*)&h; }
__device__ __forceinline__ uint pk2(float a, float b){ return (uint)f2bf(a) | ((uint)f2bf(b) << 16); }

// ---------------- one-shot bf16 conversion of both weight matrices ----------------
__global__ __launch_bounds__(256) void wcvt(const float* __restrict__ Wp,
    const float* __restrict__ Wr, ushort* __restrict__ Wpb, ushort* __restrict__ Wrb) {
  int i = blockIdx.x*256 + threadIdx.x;
  float4 a = *(const float4*)(Wp + (size_t)i*4);
  float4 b = *(const float4*)(Wr + (size_t)i*4);
  *(uint2*)(Wpb + (size_t)i*4) = make_uint2(pk2(a.x,a.y), pk2(a.z,a.w));
  *(uint2*)(Wrb + (size_t)i*4) = make_uint2(pk2(b.x,b.y), pk2(b.z,b.w));
}

// ---------------- MFMA sims: one wave computes 8 sims for 32 points ----------------
__device__ __forceinline__ void sims_mfma(const ushort* __restrict__ nb_base,
    const ushort* __restrict__ cnb, int lane, float* s) {
  const int pcol = lane & 31;
  const int kb   = (lane >> 5) << 3;
  const ushort* arow = cnb + (size_t)(pcol & 7)*CC + kb;
  const ushort* brow = nb_base + (size_t)pcol*CC + kb;
  const bool azero = pcol >= 8;
  bf16x8 z;
  #pragma unroll
  for (int j = 0; j < 8; ++j) z[j] = (__bf16)0.0f;
  f32x16 acc;
  #pragma unroll
  for (int r = 0; r < 16; ++r) acc[r] = 0.0f;
  #pragma unroll
  for (int st = 0; st < 16; ++st) {
    bf16x8 af = *(const bf16x8*)(arow + st*16);
    if (azero) af = z;
    bf16x8 bg = *(const bf16x8*)(brow + st*16);
    acc = __builtin_amdgcn_mfma_f32_32x32x16_bf16(af, bg, acc, 0, 0, 0);
  }
  float sh[4];
  #pragma unroll
  for (int r = 0; r < 4; ++r) sh[r] = __shfl_xor(acc[r], 32);
  const bool hi = lane >= 32;
  #pragma unroll
  for (int r = 0; r < 4; ++r) {
    s[r]     = hi ? sh[r]  : acc[r];
    s[r + 4] = hi ? acc[r] : sh[r];
  }
}

// ---------------- MFMA GEMM, BK=32: 28 KB LDS -> 4 blocks/CU target ----------------
// Same K-accumulation order as BK=64 version (bitwise-identical output).
// PROJ: D bf16 (nodes) + per-row rnorm.
// !PROJ: own W8 (sims+softmax, waves 0-3, under tile-0 staging); D fp32 NT + W8@CR.
// Swizzle (64-B rows): physical 16B-chunk = logical ^ ((row>>1)&3), both sides.
template<bool PROJ>
__global__ __launch_bounds__(512) void gemm_bf16(const float* __restrict__ A,
    const ushort* __restrict__ Wb, const float* __restrict__ bias,
    void* __restrict__ Dv, float* __restrict__ rnorm,
    const float* __restrict__ CR,
    const ushort* __restrict__ nbf, const ushort* __restrict__ cnormbf) {
  __shared__ __align__(16) char AlB[128*32*2];   // 8 KB
  __shared__ __align__(16) char WlB[256*32*2];   // 16 KB
  __shared__ __align__(16) float shr8[128][8];   // 4 KB: PROJ rnp cols / !PROJ W8
  const int t  = threadIdx.x;
  const int p0 = blockIdx.x * 128;
  const int lane = t & 63;
  const int w  = t >> 6;
  const int wr = w >> 2, wc = w & 3;

  // ---- A staging map: 1 chunk/thread. linear global f32 source, swizzled LDS dest
  const int as_row = t >> 2, as_c = t & 3;
  const int aoff = as_row*64 + ((as_c << 4) ^ (((as_row >> 1) & 3) << 4));
  const int agb  = (p0 + as_row)*CC + as_c*8;
  // ---- W staging map: 2 chunks/thread. inverse-swizzled global source, linear LDS dest
  int wgb[2]; int wdo[2];
  #pragma unroll
  for (int i = 0; i < 2; ++i) {
    int S = i*512 + t, row = S >> 2, sc = S & 3;
    wgb[i] = row*CC + ((sc ^ ((row >> 1) & 3)) << 3);
    wdo[i] = S*16;
  }
  const int arow = (wr << 6) + (lane & 31);
  const int brow = (wc << 6) + (lane & 31);
  const int chl  = lane >> 5;                    // logical chunk low bit

  uint4 ra;
  auto LOADA = [&](int ks) {             // f32 -> packed bf16 regs (8 elems)
    float4 v0 = *(const float4*)(A + agb + ks*32);
    float4 v1 = *(const float4*)(A + agb + ks*32 + 4);
    ra = make_uint4(pk2(v0.x,v0.y), pk2(v0.z,v0.w), pk2(v1.x,v1.y), pk2(v1.z,v1.w));
  };
  auto WRITEA = [&]() { *(uint4*)(AlB + aoff) = ra; };
  auto STAGEW = [&](int ks) {
    #pragma unroll
    for (int i = 0; i < 2; ++i)
      __builtin_amdgcn_global_load_lds(
          (const __attribute__((address_space(1))) uint*)(Wb + wgb[i] + ks*32),
          (__attribute__((address_space(3))) uint*)(WlB + wdo[i]), 16, 0, 0);
  };

  f32x16 acc[2][2];
  #pragma unroll
  for (int fm = 0; fm < 2; ++fm)
    #pragma unroll
    for (int fn = 0; fn < 2; ++fn)
      #pragma unroll
      for (int r = 0; r < 16; ++r) acc[fm][fn][r] = 0.0f;

  // ---- prologue: stage tile 0 (+ !PROJ: this block's W8 under the staging loads)
  LOADA(0); STAGEW(0);
  if constexpr (!PROJ) {
    if (w < 4) {                         // waves 0-3: 32 points each
      const size_t p0w = (size_t)p0 + w*32;
      float s[8];
      sims_mfma(nbf + p0w*CC, cnormbf + (size_t)(blockIdx.x >> 7)*NCLUS*CC, lane, s);
      const int pcol = lane & 31;
      const float rn10 = rnorm[p0w + pcol] * 10.0f;
      float m = -1e30f;
      #pragma unroll
      for (int k = 0; k < 8; ++k) { s[k] *= rn10; m = fmaxf(m, s[k]); }
      float wgt[8], sw = 0.0f;
      #pragma unroll
      for (int k = 0; k < 8; ++k) { wgt[k] = __expf(s[k] - m); sw += wgt[k]; }
      const float inv = 1.0f / sw;
      if (lane < 32) {
        float* wp = &shr8[w*32 + pcol][0];
        *(float4*)(wp)     = make_float4(wgt[0]*inv, wgt[1]*inv, wgt[2]*inv, wgt[3]*inv);
        *(float4*)(wp + 4) = make_float4(wgt[4]*inv, wgt[5]*inv, wgt[6]*inv, wgt[7]*inv);
      }
    }
  }
  WRITEA();
  __syncthreads();                       // tile 0 ready (+ W8 visible)

  #pragma unroll
  for (int ks = 0; ks < 8; ++ks) {
    if (ks < 7) LOADA(ks + 1);           // next A in flight under MFMAs
    bf16x8 af[2][2], bg[2][2];
    #pragma unroll
    for (int fm = 0; fm < 2; ++fm)
      #pragma unroll
      for (int kq = 0; kq < 2; ++kq) {
        int row = arow + (fm << 5);
        int ch  = ((kq << 1) + chl) ^ ((row >> 1) & 3);
        af[fm][kq] = *(const bf16x8*)(AlB + row*64 + (ch << 4));
      }
    #pragma unroll
    for (int fn = 0; fn < 2; ++fn)
      #pragma unroll
      for (int kq = 0; kq < 2; ++kq) {
        int row = brow + (fn << 5);
        int ch  = ((kq << 1) + chl) ^ ((row >> 1) & 3);
        bg[fn][kq] = *(const bf16x8*)(WlB + row*64 + (ch << 4));
      }
    #pragma unroll
    for (int kq = 0; kq < 2; ++kq)
      #pragma unroll
      for (int fm = 0; fm < 2; ++fm)
        #pragma unroll
        for (int fn = 0; fn < 2; ++fn)
          acc[fm][fn] = __builtin_amdgcn_mfma_f32_32x32x16_bf16(
              af[fm][kq], bg[fn][kq], acc[fm][fn], 0, 0, 0);
    if (ks < 7) {
      __syncthreads();                   // tile ks reads complete
      STAGEW(ks + 1);
      WRITEA();
      __syncthreads();                   // tile ks+1 ready
    }
  }

  // --- epilogue ---
  const int colb = (wc << 6) + (lane & 31);
  const float b0 = bias[colb], b1 = bias[colb + 32];
  float cr0[8], cr1[8];
  if constexpr (!PROJ) {
    const float* crb = CR + (size_t)(blockIdx.x >> 7)*NCLUS*CC;
    #pragma unroll
    for (int k = 0; k < 8; ++k) { cr0[k] = crb[k*CC + colb]; cr1[k] = crb[k*CC + colb + 32]; }
  }
  #pragma unroll
  for (int fm = 0; fm < 2; ++fm) {
    float rs[16];
    #pragma unroll
    for (int r = 0; r < 16; ++r) {
      int rowin = (r & 3) + ((r >> 2) << 3) + ((lane >> 5) << 2);
      int r128  = (wr << 6) + (fm << 5) + rowin;
      size_t grow = (size_t)(p0 + r128);
      float v0 = acc[fm][0][r] + b0;
      float v1 = acc[fm][1][r] + b1;
      if constexpr (PROJ) {
        ushort* D = (ushort*)Dv;
        D[grow*CC + colb]      = f2bf(v0);
        D[grow*CC + colb + 32] = f2bf(v1);
        rs[r] = v0*v0 + v1*v1;
      } else {
        float4 ua = *(const float4*)&shr8[r128][0];   // W8 from LDS (broadcast)
        float4 ub = *(const float4*)&shr8[r128][4];
        v0 += ua.x*cr0[0] + ua.y*cr0[1] + ua.z*cr0[2] + ua.w*cr0[3]
            + ub.x*cr0[4] + ub.y*cr0[5] + ub.z*cr0[6] + ub.w*cr0[7];
        v1 += ua.x*cr1[0] + ua.y*cr1[1] + ua.z*cr1[2] + ua.w*cr1[3]
            + ub.x*cr1[4] + ub.y*cr1[5] + ub.z*cr1[6] + ub.w*cr1[7];
        float* D = (float*)Dv;
        __builtin_nontemporal_store(v0, &D[grow*CC + colb]);
        __builtin_nontemporal_store(v1, &D[grow*CC + colb + 32]);
      }
    }
    if constexpr (PROJ) {
      #pragma unroll
      for (int m = 1; m < 32; m <<= 1)
        #pragma unroll
        for (int r = 0; r < 16; ++r) rs[r] += __shfl_xor(rs[r], m);
      if ((lane & 31) == 0) {
        #pragma unroll
        for (int r = 0; r < 16; ++r) {
          int rowin = (r & 3) + ((r >> 2) << 3) + ((lane >> 5) << 2);
          shr8[(wr << 6) + (fm << 5) + rowin][wc] = rs[r];
        }
      }
    }
  }
  if constexpr (PROJ) {
    __syncthreads();
    if (t < 128) {
      float s = shr8[t][0] + shr8[t][1] + shr8[t][2] + shr8[t][3];
      rnorm[p0 + t] = 1.0f / fmaxf(sqrtf(s), 1e-12f);
    }
  }
}

// ---------------- merged: init centers from nodes + norm + zero accs ----------------
__global__ __launch_bounds__(256) void centers_init(const ushort* __restrict__ nbf,
    ushort* __restrict__ cnormbf, float* __restrict__ accs, float* __restrict__ counts) {
  const int idxs[8] = {0, 2340, 4680, 7021, 9361, 11702, 14042, 16383};
  const int row = blockIdx.x;            // b*8 + k
  const int b = row >> 3, k = row & 7;
  const int t = threadIdx.x;
  float c = __uint_as_float(((uint)nbf[((size_t)b*PP + idxs[k])*CC + t]) << 16);
  float s2 = c*c;
  #pragma unroll
  for (int o = 32; o; o >>= 1) s2 += __shfl_xor(s2, o);
  __shared__ float ps[4];
  if ((t & 63) == 0) ps[t >> 6] = s2;
  __syncthreads();
  float tot = ps[0] + ps[1] + ps[2] + ps[3];
  cnormbf[(size_t)row*CC + t] = f2bf(c * (1.0f / fmaxf(sqrtf(tot), 1e-12f)));
  #pragma unroll
  for (int s = 0; s < 8; ++s) accs[((size_t)s*64 + row)*CC + t] = 0.0f;
  if (t == 0) counts[row] = 0.0f;
}

// accs -> cnormbf; DO_CR: also CR[row][t] = dot(center_row, Wr[t]); re-zero accs/counts
template<bool DO_CR>
__global__ __launch_bounds__(256) void centers_finalize(float* __restrict__ accs,
    float* __restrict__ counts, ushort* __restrict__ cnormbf,
    const float* __restrict__ Wr, float* __restrict__ CR) {
  __shared__ float cenL[CC];
  const int row = blockIdx.x;
  const int t = threadIdx.x;
  float v = 0.0f;
  #pragma unroll
  for (int s = 0; s < 8; ++s) {
    v += accs[((size_t)s*64 + row)*CC + t];
    accs[((size_t)s*64 + row)*CC + t] = 0.0f;
  }
  float cnt = fmaxf(counts[row], 1.0f);
  float c = v / cnt;
  if constexpr (DO_CR) cenL[t] = c;
  float s2 = c*c;
  #pragma unroll
  for (int o = 32; o; o >>= 1) s2 += __shfl_xor(s2, o);
  __shared__ float ps[4];
  if ((t & 63) == 0) ps[t >> 6] = s2;
  __syncthreads();
  float tot = ps[0] + ps[1] + ps[2] + ps[3];
  cnormbf[(size_t)row*CC + t] = f2bf(c * (1.0f / fmaxf(sqrtf(tot), 1e-12f)));
  if (t == 0) counts[row] = 0.0f;
  if constexpr (DO_CR) {
    float a = 0.0f;
    const float* wrow = Wr + (size_t)t*CC;
    #pragma unroll 4
    for (int j = 0; j < CC; j += 4) {
      float4 wv = *(const float4*)(wrow + j);
      float4 cv = *(const float4*)&cenL[j];
      a += cv.x*wv.x + cv.y*wv.y + cv.z*wv.z + cv.w*wv.w;
    }
    CR[(size_t)row*CC + t] = a;
  }
}

// ---------------- assign: MFMA sims + argmax, column-parallel accumulate ----------------
__global__ __launch_bounds__(256) void assign_mfma(const ushort* __restrict__ nbf,
    const ushort* __restrict__ cnormbf, float* __restrict__ accs, float* __restrict__ counts) {
  __shared__ int assignL[128];
  __shared__ int cntL[NCLUS];
  const int t = threadIdx.x;
  const int wave = t >> 6, lane = t & 63;
  const int b = blockIdx.x >> 7;
  if (t < NCLUS) cntL[t] = 0;
  __syncthreads();
  const size_t p0w = (size_t)blockIdx.x*128 + wave*32;
  float s[8];
  sims_mfma(nbf + p0w*CC, cnormbf + (size_t)b*NCLUS*CC, lane, s);
  if (lane < 32) {
    int best = 0; float bs = s[0];
    #pragma unroll
    for (int k = 1; k < 8; ++k) if (s[k] > bs) { bs = s[k]; best = k; }
    assignL[wave*32 + lane] = best;
    atomicAdd(&cntL[best], 1);
  }
  __syncthreads();
  float a[8] = {0,0,0,0,0,0,0,0};
  const ushort* base = nbf + (size_t)blockIdx.x*128*CC;
  #pragma unroll 4
  for (int i = 0; i < 128; ++i) {
    int asg = __builtin_amdgcn_readfirstlane(assignL[i]);
    float v = __uint_as_float(((uint)base[(size_t)i*CC + t]) << 16);
    if      (asg == 0) a[0] += v;
    else if (asg == 1) a[1] += v;
    else if (asg == 2) a[2] += v;
    else if (asg == 3) a[3] += v;
    else if (asg == 4) a[4] += v;
    else if (asg == 5) a[5] += v;
    else if (asg == 6) a[6] += v;
    else               a[7] += v;
  }
  const int slot = blockIdx.x & 7;
  float* dst = accs + ((size_t)slot*BB + b)*NCLUS*CC;
  #pragma unroll
  for (int k = 0; k < 8; ++k) atomicAdd(&dst[k*CC + t], a[k]);
  if (t < NCLUS) atomicAdd(&counts[b*NCLUS + t], (float)cntL[t]);
}

extern "C" void kernel_launch(void* const* d_in, const int* in_sizes, int n_in,
                              void* d_out, int out_size, void* d_ws, size_t ws_size,
                              hipStream_t stream) {
  const float* F_p      = (const float*)d_in[0];
  const float* proj_w   = (const float*)d_in[1];
  const float* proj_b   = (const float*)d_in[2];
  const float* refine_w = (const float*)d_in[3];
  const float* refine_b = (const float*)d_in[4];
  float* out = (float*)d_out;

  char* ws = (char*)d_ws;
  ushort* nbf    = (ushort*)ws;                                  // 64 MiB
  float*  rnorm  = (float*)(ws + (size_t)BPROWS*CC*2);           // 512 KiB
  float*  accs   = rnorm + BPROWS;                               // 512 KiB
  float*  counts = accs + 8*BB*NCLUS*CC;                         // 256 B
  float*  CR     = counts + 64;                                  // 64 KiB
  ushort* cnormbf= (ushort*)(CR + BB*NCLUS*CC);                  // 32 KiB
  ushort* Wpb    = cnormbf + BB*NCLUS*CC;                        // 128 KiB
  ushort* Wrb    = Wpb + CC*CC;                                  // 128 KiB

  wcvt<<<64, 256, 0, stream>>>(proj_w, refine_w, Wpb, Wrb);
  gemm_bf16<true><<<1024, 512, 0, stream>>>(F_p, Wpb, proj_b, nbf, rnorm,
                                            nullptr, nullptr, nullptr);
  centers_init<<<64, 256, 0, stream>>>(nbf, cnormbf, accs, counts);
  for (int it = 0; it < 3; ++it) {
    assign_mfma<<<1024, 256, 0, stream>>>(nbf, cnormbf, accs, counts);
    if (it < 2) centers_finalize<false><<<64, 256, 0, stream>>>(accs, counts, cnormbf, nullptr, nullptr);
    else        centers_finalize<true ><<<64, 256, 0, stream>>>(accs, counts, cnormbf, refine_w, CR);
  }
  gemm_bf16<false><<<1024, 512, 0, stream>>>(F_p, Wrb, refine_b, out, rnorm,
                                             CR, nbf, cnormbf);
}